// Round 3
// baseline (7164.669 us; speedup 1.0000x reference)
//
#include <hip/hip_runtime.h>
#include <hip/hip_bf16.h>
#include <stdint.h>

// WiredRNN: h_{t+1} = tanh([h_t | x_t] @ [Wr;Wi] + b), B=32, L=8192, C=128, U=256, OUT=64.
// Sequential over t -> one persistent workgroup per batch element (32 WGs, 1024 thr).
// Weights masked once and held in registers as packed f16 (lossless: inputs are
// bf16-rounded fp32); per-step matvec via v_dot2_f32_f16.
// Inputs: fp32 buffers (established R1/R2: bf16 reinterpretation NaNs; sniffer returned 0).
// Output: fp32 (reference output dtype is float32; R2's bf16 writes read as fp32 produced
// the position-shifted ~1.9 absmax signature).

#define NB 32
#define SL 8192
#define NC 128
#define NU 256
#define NO 64
#define NK 384        // concatenated [h(256) | x(128)]
#define KCH 96        // k-chunk per thread group (NK / 4)
#define NPAIR 48      // KCH / 2 packed pairs per thread

typedef _Float16 h16;
typedef __attribute__((ext_vector_type(2))) _Float16 h16x2;

// M_in is Bernoulli{0,1}. As fp32, every dword is 0x00000000 or 0x3F800000.
// As packed bf16, dwords 0x00003F80 ((1,0) pair) / 0x3F803F80 ((1,1) pair) occur ~50%.
__global__ void detect_dtype_kernel(const uint32_t* __restrict__ m_raw,
                                    int* __restrict__ flag) {
    __shared__ int found;
    if (threadIdx.x == 0) found = 0;
    __syncthreads();
    int local = 0;
    for (int i = threadIdx.x; i < 4096; i += 256) {
        uint32_t d = m_raw[i];
        if (d == 0x00003F80u || d == 0x3F803F80u) local = 1;
    }
    if (local) atomicOr(&found, 1);
    __syncthreads();
    if (threadIdx.x == 0) *flag = found;   // 1 = bf16 inputs, 0 = fp32 inputs
}

__device__ __forceinline__ float ldf(const void* p, long i, int isbf) {
    return isbf ? __bfloat162float(((const __hip_bfloat16*)p)[i])
                : ((const float*)p)[i];
}

__global__ __launch_bounds__(1024, 4) void rnn_scan_kernel(
    const void* __restrict__ x,      // [B, L, C]
    const void* __restrict__ W_in,   // [C, U]
    const void* __restrict__ W_rec,  // [U, U]
    const void* __restrict__ bias,   // [U]
    const void* __restrict__ M_in,   // [C, U]
    const void* __restrict__ M_rec,  // [U, U]
    const int* __restrict__ flag,
    float* __restrict__ out)         // fp32: [B*L*NO] readout ++ [B*U] h_last
{
    const int tid = threadIdx.x;
    const int b   = blockIdx.x;
    const int u   = tid & (NU - 1);   // output unit this thread contributes to
    const int kc  = tid >> 8;         // which k-chunk (0..3)
    const int ks  = kc * KCH;
    const int isbf = *flag;           // uniform

    __shared__ __align__(16) h16 vec[NK];      // [h | x_t] in f16
    __shared__ float partial[4][NU];

    // ---- one-time: masked weights into registers as packed f16 pairs ----
    // Wtot[k][u] = k < NU ? W_rec[k][u]*M_rec[k][u] : W_in[k-NU][u]*M_in[k-NU][u]
    h16x2 w[NPAIR];
#pragma unroll
    for (int j = 0; j < NPAIR; ++j) {
        const int k0 = ks + 2 * j;
        const int k1 = k0 + 1;
        float w0, w1;
        if (k0 < NU) w0 = ldf(W_rec, k0 * NU + u, isbf) * ldf(M_rec, k0 * NU + u, isbf);
        else         w0 = ldf(W_in, (k0 - NU) * NU + u, isbf) * ldf(M_in, (k0 - NU) * NU + u, isbf);
        if (k1 < NU) w1 = ldf(W_rec, k1 * NU + u, isbf) * ldf(M_rec, k1 * NU + u, isbf);
        else         w1 = ldf(W_in, (k1 - NU) * NU + u, isbf) * ldf(M_in, (k1 - NU) * NU + u, isbf);
        h16x2 t2; t2[0] = (h16)w0; t2[1] = (h16)w1;
        w[j] = t2;
    }

    const float breg = (tid < NU) ? ldf(bias, u, isbf) : 0.0f;
    const long xbase = (long)b * SL * NC;

    // ---- init: h0 = 0, stage x_0 ----
    if (tid < NU) {
        vec[tid] = (h16)0.f;
    } else if (tid < NU + NC) {
        vec[tid] = (h16)ldf(x, xbase + (tid - NU), isbf);
    }
    __syncthreads();

    const bool xthr = (tid >= NU) && (tid < NU + NC);

    for (int t = 0; t < SL; ++t) {
        // issue next-step x load early; consumed after the barrier (latency hidden)
        float xr = 0.f;
        if (xthr && (t + 1 < SL))
            xr = ldf(x, xbase + (long)(t + 1) * NC + (tid - NU), isbf);

        // partial dot over this thread's k-chunk (wave-uniform LDS reads -> broadcast)
        const h16x2* v2 = (const h16x2*)(&vec[ks]);
        float acc = 0.f;
#pragma unroll
        for (int j = 0; j < NPAIR; ++j) {
#if __has_builtin(__builtin_amdgcn_fdot2)
            acc = __builtin_amdgcn_fdot2(v2[j], w[j], acc, false);
#else
            acc += (float)v2[j][0] * (float)w[j][0] + (float)v2[j][1] * (float)w[j][1];
#endif
        }
        partial[kc][u] = acc;
        __syncthreads();

        if (tid < NU) {
            float s = partial[0][u] + partial[1][u] + partial[2][u] + partial[3][u] + breg;
            float hn = tanhf(s);
            vec[u] = (h16)hn;                       // new h for next step
            if (u >= NU - NO)                        // motor neurons -> readout
                out[((long)b * SL + t) * NO + (u - (NU - NO))] = hn;
            if (t == SL - 1)                         // h_last
                out[(long)NB * SL * NO + (long)b * NU + u] = hn;
        } else if (xthr && (t + 1 < SL)) {
            vec[tid] = (h16)xr;                      // stage x_{t+1}
        }
        __syncthreads();
    }
}

extern "C" void kernel_launch(void* const* d_in, const int* in_sizes, int n_in,
                              void* d_out, int out_size, void* d_ws, size_t ws_size,
                              hipStream_t stream) {
    (void)in_sizes; (void)n_in; (void)ws_size; (void)out_size;
    const void* x     = d_in[0];
    const void* W_in  = d_in[1];
    const void* W_rec = d_in[2];
    const void* bias  = d_in[3];
    const void* M_in  = d_in[4];
    const void* M_rec = d_in[5];
    float* out = (float*)d_out;
    int* flag = (int*)d_ws;   // d_ws is re-poisoned each call; detect kernel rewrites it

    detect_dtype_kernel<<<dim3(1), dim3(256), 0, stream>>>((const uint32_t*)M_in, flag);
    rnn_scan_kernel<<<dim3(NB), dim3(1024), 0, stream>>>(x, W_in, W_rec, bias, M_in, M_rec,
                                                         flag, out);
}

// Round 4
// 5540.187 us; speedup vs baseline: 1.2932x; 1.2932x over previous
//
#include <hip/hip_runtime.h>
#include <hip/hip_bf16.h>
#include <stdint.h>

// WiredRNN: h_{t+1} = tanh([h_t | x_t] @ [Wr;Wi] + b), B=32, L=8192, C=128, U=256, OUT=64.
// R4 structure:
//   1) xw_gemm_kernel: full-chip GEMM XW[b,t,u] = x[b,t,:] @ (W_in*M_in) + bias  -> d_ws (f16)
//   2) rnn_scan_xw:    32 persistent WGs (one per batch), K=256 recurrent dot via fdot2,
//                      fast exp2-based tanh. Inputs fp32 (established R1-R3), output fp32.
// Fallback (ws_size too small): R3's proven K=384 scan.

#define NB 32
#define SL 8192
#define NC 128
#define NU 256
#define NO 64
#define NK 384
#define GR 64          // rows per GEMM workgroup

typedef _Float16 h16;
typedef __attribute__((ext_vector_type(2))) _Float16 h16x2;

__device__ __forceinline__ float fdot2f(h16x2 a, h16x2 b, float c) {
#if __has_builtin(__builtin_amdgcn_fdot2)
    return __builtin_amdgcn_fdot2(a, b, c, false);
#else
    return c + (float)a[0] * (float)b[0] + (float)a[1] * (float)b[1];
#endif
}

// tanh(x) = 1 - 2/(e^{2x}+1);  e^{2x} = 2^{x*2*log2(e)}.  v_exp_f32 + v_rcp_f32.
__device__ __forceinline__ float ftanh(float x) {
#if __has_builtin(__builtin_amdgcn_exp2f) && __has_builtin(__builtin_amdgcn_rcpf)
    float e = __builtin_amdgcn_exp2f(x * 2.8853900817779268f);
    return 1.0f - 2.0f * __builtin_amdgcn_rcpf(e + 1.0f);
#else
    return tanhf(x);
#endif
}

// ---------------- XW precompute GEMM ----------------
// grid = (B*SL)/GR = 4096 WGs x 256 threads. Thread u holds Wi column u (masked, f16 pairs)
// in registers; x tile staged in LDS as f16; 64 fdot2 per row, broadcast LDS reads.
__global__ __launch_bounds__(256, 4) void xw_gemm_kernel(
    const float* __restrict__ x,      // [B*SL, NC]
    const float* __restrict__ W_in,   // [NC, NU]
    const float* __restrict__ bias,   // [NU]
    const float* __restrict__ M_in,   // [NC, NU]
    h16* __restrict__ xw)             // [B*SL, NU]
{
    const int u = threadIdx.x;
    const long row0 = (long)blockIdx.x * GR;
    __shared__ h16 xs[GR * NC];       // 16 KB

    // stage x tile (coalesced fp32 -> f16)
    for (int i = u; i < GR * NC; i += 256)
        xs[i] = (h16)x[row0 * NC + i];

    // Wi column u, masked, packed pairs (coalesced global reads across lanes)
    h16x2 wc[NC / 2];
#pragma unroll
    for (int j = 0; j < NC / 2; ++j) {
        const int k0 = 2 * j, k1 = 2 * j + 1;
        float w0 = W_in[k0 * NU + u] * M_in[k0 * NU + u];
        float w1 = W_in[k1 * NU + u] * M_in[k1 * NU + u];
        h16x2 t; t[0] = (h16)w0; t[1] = (h16)w1;
        wc[j] = t;
    }
    const float bs = bias[u];
    __syncthreads();

    for (int r = 0; r < GR; ++r) {
        const h16x2* xv = (const h16x2*)&xs[r * NC];   // wave-uniform -> broadcast reads
        float acc = bs;
#pragma unroll
        for (int j = 0; j < NC / 2; ++j)
            acc = fdot2f(xv[j], wc[j], acc);
        xw[(row0 + r) * NU + u] = (h16)acc;
    }
}

// ---------------- recurrent scan (K = 256) ----------------
__global__ __launch_bounds__(1024, 4) void rnn_scan_xw(
    const float* __restrict__ W_rec,  // [NU, NU]
    const float* __restrict__ M_rec,  // [NU, NU]
    const h16* __restrict__ xw,       // [B*SL, NU] (bias folded in)
    float* __restrict__ out)          // [B*SL*NO] readout ++ [B*NU] h_last
{
    const int tid = threadIdx.x;
    const int b   = blockIdx.x;
    const int u   = tid & (NU - 1);
    const int kc  = tid >> 8;         // 0..3
    const int ks  = kc * 64;

    __shared__ __align__(16) h16 vec[NU];      // h state in f16
    __shared__ float partial[NU][4];

    // masked recurrent weights, packed f16 pairs (32 per thread)
    h16x2 w[32];
#pragma unroll
    for (int j = 0; j < 32; ++j) {
        const int k0 = ks + 2 * j, k1 = k0 + 1;
        float w0 = W_rec[k0 * NU + u] * M_rec[k0 * NU + u];
        float w1 = W_rec[k1 * NU + u] * M_rec[k1 * NU + u];
        h16x2 t; t[0] = (h16)w0; t[1] = (h16)w1;
        w[j] = t;
    }

    if (tid < NU) vec[tid] = (h16)0.f;
    __syncthreads();

    const long xwbase = (long)b * SL * NU;

    for (int t = 0; t < SL; ++t) {
        // xw for this step: issued before the dot loop, consumed in phase 2 (latency hidden)
        float xwv = 0.f;
        if (tid < NU) xwv = (float)xw[xwbase + (long)t * NU + tid];

        // phase 1: partial dot over this thread's 64-wide k-chunk (broadcast LDS reads)
        const h16x2* v2 = (const h16x2*)(&vec[ks]);
        float acc = 0.f;
#pragma unroll
        for (int j = 0; j < 32; ++j)
            acc = fdot2f(v2[j], w[j], acc);
        partial[u][kc] = acc;
        __syncthreads();

        // phase 2: reduce + tanh + state update (threads 0..255)
        if (tid < NU) {
            const float4 p = *(const float4*)&partial[u][0];
            const float s = (p.x + p.y) + (p.z + p.w) + xwv;
            const float hn = ftanh(s);
            vec[u] = (h16)hn;
            if (u >= NU - NO)
                out[((long)b * SL + t) * NO + (u - (NU - NO))] = hn;
            if (t == SL - 1)
                out[(long)NB * SL * NO + (long)b * NU + u] = hn;
        }
        __syncthreads();
    }
}

// ---------------- fallback (R3, proven): K=384 scan reading x directly ----------------
__global__ __launch_bounds__(1024, 4) void rnn_scan_fallback(
    const float* __restrict__ x,
    const float* __restrict__ W_in,
    const float* __restrict__ W_rec,
    const float* __restrict__ bias,
    const float* __restrict__ M_in,
    const float* __restrict__ M_rec,
    float* __restrict__ out)
{
    const int tid = threadIdx.x;
    const int b   = blockIdx.x;
    const int u   = tid & (NU - 1);
    const int kc  = tid >> 8;
    const int ks  = kc * 96;

    __shared__ __align__(16) h16 vec[NK];
    __shared__ float partial[4][NU];

    h16x2 w[48];
#pragma unroll
    for (int j = 0; j < 48; ++j) {
        const int k0 = ks + 2 * j, k1 = k0 + 1;
        float w0, w1;
        if (k0 < NU) w0 = W_rec[k0 * NU + u] * M_rec[k0 * NU + u];
        else         w0 = W_in[(k0 - NU) * NU + u] * M_in[(k0 - NU) * NU + u];
        if (k1 < NU) w1 = W_rec[k1 * NU + u] * M_rec[k1 * NU + u];
        else         w1 = W_in[(k1 - NU) * NU + u] * M_in[(k1 - NU) * NU + u];
        h16x2 t; t[0] = (h16)w0; t[1] = (h16)w1;
        w[j] = t;
    }
    const float breg = (tid < NU) ? bias[u] : 0.0f;
    const long xbase = (long)b * SL * NC;

    if (tid < NU) vec[tid] = (h16)0.f;
    else if (tid < NU + NC) vec[tid] = (h16)x[xbase + (tid - NU)];
    __syncthreads();

    const bool xthr = (tid >= NU) && (tid < NU + NC);
    for (int t = 0; t < SL; ++t) {
        float xr = 0.f;
        if (xthr && (t + 1 < SL)) xr = x[xbase + (long)(t + 1) * NC + (tid - NU)];

        const h16x2* v2 = (const h16x2*)(&vec[ks]);
        float acc = 0.f;
#pragma unroll
        for (int j = 0; j < 48; ++j) acc = fdot2f(v2[j], w[j], acc);
        partial[kc][u] = acc;
        __syncthreads();

        if (tid < NU) {
            float s = partial[0][u] + partial[1][u] + partial[2][u] + partial[3][u] + breg;
            float hn = ftanh(s);
            vec[u] = (h16)hn;
            if (u >= NU - NO) out[((long)b * SL + t) * NO + (u - (NU - NO))] = hn;
            if (t == SL - 1)  out[(long)NB * SL * NO + (long)b * NU + u] = hn;
        } else if (xthr && (t + 1 < SL)) {
            vec[tid] = (h16)xr;
        }
        __syncthreads();
    }
}

extern "C" void kernel_launch(void* const* d_in, const int* in_sizes, int n_in,
                              void* d_out, int out_size, void* d_ws, size_t ws_size,
                              hipStream_t stream) {
    (void)in_sizes; (void)n_in; (void)out_size;
    const float* x     = (const float*)d_in[0];
    const float* W_in  = (const float*)d_in[1];
    const float* W_rec = (const float*)d_in[2];
    const float* bias  = (const float*)d_in[3];
    const float* M_in  = (const float*)d_in[4];
    const float* M_rec = (const float*)d_in[5];
    float* out = (float*)d_out;

    const size_t xw_bytes = (size_t)NB * SL * NU * sizeof(h16);   // 134,217,728
    if (ws_size >= xw_bytes) {
        h16* xw = (h16*)d_ws;
        xw_gemm_kernel<<<dim3((NB * SL) / GR), dim3(256), 0, stream>>>(x, W_in, bias, M_in, xw);
        rnn_scan_xw<<<dim3(NB), dim3(1024), 0, stream>>>(W_rec, M_rec, xw, out);
    } else {
        rnn_scan_fallback<<<dim3(NB), dim3(1024), 0, stream>>>(x, W_in, W_rec, bias, M_in, M_rec, out);
    }
}